// Round 11
// baseline (1398.230 us; speedup 1.0000x reference)
//
#include <hip/hip_runtime.h>

// MultiHeadAttention: fp32 in/out, bf16 MFMA compute. B=4 T=2048 C=2048 H=16 Dh=128.
// ws = 6 SLOT = 50.33 MB (SLOT = 4.19M bf16 = 8.39 MB).
// Slot chain: cvt_x -> xb[0-3], wtQK[4-5] -> gemm_qk (bf16 A) -> qk in d_out.
// Then (xb dead): wtV[0], vt[2-5] via fp32-A gemm_xa<2>; flash (2 dispatches,
// batches {0,1} then {2,3} -- dispatch boundary orders y-writes vs vt-reads):
// vt(2+b) -> y[b]; wtP[4]; proj reads y[0-3] contiguous.
// Flash v3: QBLK=128 (32 q-rows/wave), KVBLK=64, 512 blocks/dispatch (3/CU,
// 48KB LDS). Round-9 PMC: time invariant to occupancy, MFMA 22% VALU 40%,
// 0 bank-conflict -> LDS-pipe-bound; QBLK=128 halves K/V fragment re-reads
// per q-row. sP is wave-private -> no barrier after P-write (3 bar/iter).

using bhalf  = __bf16;
using bhalf8 = __attribute__((ext_vector_type(8))) __bf16;   // MFMA A/B frag (4 VGPRs)
using floatx4 = __attribute__((ext_vector_type(4))) float;   // MFMA C/D frag

#define MFMA16(A, B, C) __builtin_amdgcn_mfma_f32_16x16x32_bf16(A, B, C, 0, 0, 0)

__device__ __forceinline__ void gload16(const void* g, void* l) {
  // async global->LDS, 16B/lane; LDS dest = wave-uniform base + lane*16B
  __builtin_amdgcn_global_load_lds(
      (const __attribute__((address_space(1))) unsigned int*)g,
      (__attribute__((address_space(3))) unsigned int*)l, 16, 0, 0);
}

constexpr int Bn = 4, Tn = 2048, Cn = 2048, Hn = 16, Dh = 128;
constexpr int Kdim = Cn;
constexpr size_t SLOT = (size_t)Hn * Tn * Dh;  // 4,194,304 elems (8.39 MB bf16)

// ---------------- x fp32 -> bf16 (one pass; [8192][2048])
__global__ __launch_bounds__(256) void cvt_x(const float* __restrict__ in,
                                             bhalf* __restrict__ out) {
  const size_t i = ((size_t)blockIdx.x * 256 + threadIdx.x) * 8;
  const float4 a = *reinterpret_cast<const float4*>(in + i);
  const float4 b = *reinterpret_cast<const float4*>(in + i + 4);
  bhalf8 v;
  v[0] = (bhalf)a.x; v[1] = (bhalf)a.y; v[2] = (bhalf)a.z; v[3] = (bhalf)a.w;
  v[4] = (bhalf)b.x; v[5] = (bhalf)b.y; v[6] = (bhalf)b.z; v[7] = (bhalf)b.w;
  *reinterpret_cast<bhalf8*>(out + i) = v;
}

// ---------------- fp32 transpose+convert: out[c][r] = (bhalf)in[r*ldin + coff + c]
__global__ __launch_bounds__(256) void transpose_cvt(const float* __restrict__ in,
                                                     bhalf* __restrict__ out,
                                                     int ldin, int ldout, int coff) {
  __shared__ unsigned short tile[64][65];
  const int c0 = blockIdx.x * 64, r0 = blockIdx.y * 64;
  const int tx = threadIdx.x & 15, ty = threadIdx.x >> 4;
#pragma unroll
  for (int i = 0; i < 4; i++) {
    const int r = ty + i * 16;
    const float4 u = *reinterpret_cast<const float4*>(in + (size_t)(r0 + r) * ldin + coff + c0 + tx * 4);
    tile[r][tx * 4 + 0] = __builtin_bit_cast(unsigned short, (bhalf)u.x);
    tile[r][tx * 4 + 1] = __builtin_bit_cast(unsigned short, (bhalf)u.y);
    tile[r][tx * 4 + 2] = __builtin_bit_cast(unsigned short, (bhalf)u.z);
    tile[r][tx * 4 + 3] = __builtin_bit_cast(unsigned short, (bhalf)u.w);
  }
  __syncthreads();
#pragma unroll
  for (int i = 0; i < 4; i++) {
    const int c = ty + i * 16;
    ushort4 u;
    u.x = tile[tx * 4 + 0][c]; u.y = tile[tx * 4 + 1][c];
    u.z = tile[tx * 4 + 2][c]; u.w = tile[tx * 4 + 3][c];
    *reinterpret_cast<ushort4*>((unsigned short*)out + (size_t)(c0 + c) * ldout + r0 + tx * 4) = u;
  }
}

// ---------------- q,k GEMM, all-bf16: A = xb [8192][2048], Bt = W^T [4096][2048].
// 128x128x(BK=64), swizzled LDS. (256,4): R8 total (712) was lowest with this;
// R9's (256,3) revert coincided with +39us total (cross-round attribution weak;
// within-round counters will decide if it surfaces in top-5).
__global__ __launch_bounds__(256, 4) void gemm_qk(const bhalf* __restrict__ A,
                                                  const bhalf* __restrict__ Bt,
                                                  const float* __restrict__ bias,
                                                  bhalf* __restrict__ oq,
                                                  bhalf* __restrict__ ok) {
  __shared__ __align__(16) bhalf sA[128 * 64];   // 16 KB, 16B chunk c at c^(row&7)
  __shared__ __align__(16) bhalf sB[128 * 64];   // 16 KB
  const int tid = threadIdx.x;
  const int lane = tid & 63, wv = tid >> 6;
  const int ln = lane & 15, quad = lane >> 4;
  const int wr = wv >> 1, wc = wv & 1;
  const int m0 = blockIdx.y * 128, n0 = blockIdx.x * 128;

  const floatx4 fzero = {0.f, 0.f, 0.f, 0.f};
  floatx4 acc[4][4];
#pragma unroll
  for (int i = 0; i < 4; i++)
#pragma unroll
    for (int j = 0; j < 4; j++) acc[i][j] = fzero;

  const int schunk = (lane & 7) ^ ((lane >> 3) & 7);
  const bhalf* aStage = A + (size_t)(m0 + wv * 32 + (lane >> 3)) * Kdim + schunk * 8;
  const bhalf* bStage = Bt + (size_t)(n0 + wv * 32 + (lane >> 3)) * Kdim + schunk * 8;
  bhalf* sAw = &sA[(wv * 32) * 64];
  bhalf* sBw = &sB[(wv * 32) * 64];

  for (int k0 = 0; k0 < Kdim; k0 += 64) {
#pragma unroll
    for (int j = 0; j < 4; j++) gload16(aStage + (size_t)j * 8 * Kdim + k0, sAw + j * 8 * 64);
#pragma unroll
    for (int j = 0; j < 4; j++) gload16(bStage + (size_t)j * 8 * Kdim + k0, sBw + j * 8 * 64);
    __syncthreads();
#pragma unroll
    for (int ks = 0; ks < 2; ks++) {
      bhalf8 af[4], bfr[4];
#pragma unroll
      for (int mi = 0; mi < 4; mi++)
        af[mi] = *reinterpret_cast<const bhalf8*>(
            &sA[(wr * 64 + mi * 16 + ln) * 64 + ((ks * 4 + quad) ^ (ln & 7)) * 8]);
#pragma unroll
      for (int ni = 0; ni < 4; ni++)
        bfr[ni] = *reinterpret_cast<const bhalf8*>(
            &sB[(wc * 64 + ni * 16 + ln) * 64 + ((ks * 4 + quad) ^ (ln & 7)) * 8]);
#pragma unroll
      for (int mi = 0; mi < 4; mi++)
#pragma unroll
        for (int ni = 0; ni < 4; ni++)
          acc[mi][ni] = MFMA16(af[mi], bfr[ni], acc[mi][ni]);
    }
    __syncthreads();
  }

  const int b = m0 >> 11, t0 = m0 & 2047;
  const int which = n0 >> 11;             // 0: q, 1: k
  const int h = (n0 & 2047) >> 7;
  bhalf* op = which == 0 ? oq : ok;
  float bv[4];
#pragma unroll
  for (int ni = 0; ni < 4; ni++) bv[ni] = bias[n0 + wc * 64 + ni * 16 + ln];
  const size_t base = (size_t)b * (2 * SLOT) + ((size_t)h * Tn + t0) * Dh;
#pragma unroll
  for (int mi = 0; mi < 4; mi++)
#pragma unroll
    for (int ni = 0; ni < 4; ni++)
#pragma unroll
      for (int r = 0; r < 4; r++) {
        const int t = wr * 64 + mi * 16 + quad * 4 + r;  // C/D: row=quad*4+reg
        const int d = wc * 64 + ni * 16 + ln;            // C/D: col=lane&15
        op[base + (size_t)t * Dh + d] = (bhalf)(acc[mi][ni][r] + bv[ni]);
      }
}

// ---------------- v GEMM: A = x fp32 (staged fp32, cvt in frag load),
// Bt = W_v^T bf16 [2048][2048]. Swapped operands -> v^T [B,H,Dh,T] (+bias over d).
template <int MODE>
__global__ __launch_bounds__(256, 3) void gemm_xa(const float* __restrict__ A,
                                                  const bhalf* __restrict__ Bt,
                                                  const float* __restrict__ bias,
                                                  bhalf* __restrict__ oq,
                                                  bhalf* __restrict__ ok) {
  __shared__ __align__(16) float sA[128 * 64];   // 32 KB, 16B chunk c at c^(row&15)
  __shared__ __align__(16) bhalf sB[128 * 64];   // 16 KB, 16B chunk c at c^(row&7)
  const int tid = threadIdx.x;
  const int lane = tid & 63, wv = tid >> 6;
  const int ln = lane & 15, quad = lane >> 4;
  const int wr = wv >> 1, wc = wv & 1;  // 2x2 wave grid, 64x64 per wave
  const int m0 = blockIdx.y * 128, n0 = blockIdx.x * 128;

  const floatx4 fzero = {0.f, 0.f, 0.f, 0.f};
  floatx4 acc[4][4];
#pragma unroll
  for (int i = 0; i < 4; i++)
#pragma unroll
    for (int j = 0; j < 4; j++) acc[i][j] = fzero;

  const int schunkB = (lane & 7) ^ ((lane >> 3) & 7);
  const bhalf* bStage = Bt + (size_t)(n0 + wv * 32 + (lane >> 3)) * Kdim + schunkB * 8;
  bhalf* sBw = &sB[(wv * 32) * 64];
  const int rA = lane >> 4, cA = lane & 15;
  float* sAw = &sA[(wv * 32) * 64];

  for (int k0 = 0; k0 < Kdim; k0 += 64) {
#pragma unroll
    for (int j = 0; j < 8; j++) {
      const int rloc = j * 4 + rA;
      const int gc = cA ^ (rloc & 15);
      gload16(A + (size_t)(m0 + wv * 32 + rloc) * Kdim + k0 + gc * 4, sAw + (j * 4) * 64);
    }
#pragma unroll
    for (int j = 0; j < 4; j++) gload16(bStage + (size_t)j * 8 * Kdim + k0, sBw + j * 8 * 64);
    __syncthreads();
#pragma unroll
    for (int ks = 0; ks < 2; ks++) {
      bhalf8 af[4], bfr[4];
#pragma unroll
      for (int mi = 0; mi < 4; mi++) {
        const int row = wr * 64 + mi * 16 + ln;   // row&15 == ln
        const int c0c = ks * 8 + quad * 2;
        const float4 lo = *reinterpret_cast<const float4*>(&sA[row * 64 + ((c0c ^ ln) * 4)]);
        const float4 hi = *reinterpret_cast<const float4*>(&sA[row * 64 + (((c0c + 1) ^ ln) * 4)]);
        bhalf8 t;
        t[0] = (bhalf)lo.x; t[1] = (bhalf)lo.y; t[2] = (bhalf)lo.z; t[3] = (bhalf)lo.w;
        t[4] = (bhalf)hi.x; t[5] = (bhalf)hi.y; t[6] = (bhalf)hi.z; t[7] = (bhalf)hi.w;
        af[mi] = t;
      }
#pragma unroll
      for (int ni = 0; ni < 4; ni++)
        bfr[ni] = *reinterpret_cast<const bhalf8*>(
            &sB[(wc * 64 + ni * 16 + ln) * 64 + ((ks * 4 + quad) ^ (ln & 7)) * 8]);
#pragma unroll
      for (int i = 0; i < 4; i++)
#pragma unroll
        for (int j = 0; j < 4; j++) {
          if (MODE == 2)
            acc[i][j] = MFMA16(bfr[i], af[j], acc[i][j]);  // D^T: acc[ni][mi]
          else
            acc[i][j] = MFMA16(af[i], bfr[j], acc[i][j]);  // D:   acc[mi][ni]
        }
    }
    __syncthreads();
  }

  const int b = m0 >> 11, t0 = m0 & 2047;
  if (MODE == 0) {
    const int which = n0 >> 11;             // 0: q, 1: k
    const int h = (n0 & 2047) >> 7;
    bhalf* op = which == 0 ? oq : ok;
    float bv[4];
#pragma unroll
    for (int ni = 0; ni < 4; ni++) bv[ni] = bias[n0 + wc * 64 + ni * 16 + ln];
    const size_t base = (size_t)b * (2 * SLOT) + ((size_t)h * Tn + t0) * Dh;
#pragma unroll
    for (int mi = 0; mi < 4; mi++)
#pragma unroll
      for (int ni = 0; ni < 4; ni++)
#pragma unroll
        for (int r = 0; r < 4; r++) {
          const int t = wr * 64 + mi * 16 + quad * 4 + r;  // C/D: row=quad*4+reg
          const int d = wc * 64 + ni * 16 + ln;            // C/D: col=lane&15
          op[base + (size_t)t * Dh + d] = (bhalf)(acc[mi][ni][r] + bv[ni]);
        }
  } else {  // MODE 2: acc[ni][mi]; D^T row = d, col = t
    const int h = n0 >> 7;
    const size_t base = (size_t)(b * Hn + h) * Dh * Tn;
#pragma unroll
    for (int ni = 0; ni < 4; ni++)
#pragma unroll
      for (int mi = 0; mi < 4; mi++)
#pragma unroll
        for (int r = 0; r < 4; r++) {
          const int d = wc * 64 + ni * 16 + quad * 4 + r;
          const int t = t0 + wr * 64 + mi * 16 + ln;
          oq[base + (size_t)d * Tn + t] = (bhalf)(acc[ni][mi][r] + bias[n0 + d]);
        }
  }
}

// ---------------- proj GEMM: A = y bf16 [8192][2048], Bt = W_proj^T, out fp32 (+bias)
__global__ __launch_bounds__(256, 3) void gemm_proj(const bhalf* __restrict__ A,
                                                    const bhalf* __restrict__ Bt,
                                                    const float* __restrict__ bias,
                                                    float* __restrict__ of) {
  __shared__ __align__(16) bhalf sA[128 * 64];
  __shared__ __align__(16) bhalf sB[128 * 64];
  const int tid = threadIdx.x;
  const int lane = tid & 63, wv = tid >> 6;
  const int ln = lane & 15, quad = lane >> 4;
  const int wr = wv >> 1, wc = wv & 1;
  const int m0 = blockIdx.y * 128, n0 = blockIdx.x * 128;

  const floatx4 fzero = {0.f, 0.f, 0.f, 0.f};
  floatx4 acc[4][4];
#pragma unroll
  for (int i = 0; i < 4; i++)
#pragma unroll
    for (int j = 0; j < 4; j++) acc[i][j] = fzero;

  const int schunk = (lane & 7) ^ ((lane >> 3) & 7);
  const bhalf* aStage = A + (size_t)(m0 + wv * 32 + (lane >> 3)) * Kdim + schunk * 8;
  const bhalf* bStage = Bt + (size_t)(n0 + wv * 32 + (lane >> 3)) * Kdim + schunk * 8;
  bhalf* sAw = &sA[(wv * 32) * 64];
  bhalf* sBw = &sB[(wv * 32) * 64];

  for (int k0 = 0; k0 < Kdim; k0 += 64) {
#pragma unroll
    for (int j = 0; j < 4; j++) gload16(aStage + (size_t)j * 8 * Kdim + k0, sAw + j * 8 * 64);
#pragma unroll
    for (int j = 0; j < 4; j++) gload16(bStage + (size_t)j * 8 * Kdim + k0, sBw + j * 8 * 64);
    __syncthreads();
#pragma unroll
    for (int ks = 0; ks < 2; ks++) {
      bhalf8 af[4], bfr[4];
#pragma unroll
      for (int mi = 0; mi < 4; mi++)
        af[mi] = *reinterpret_cast<const bhalf8*>(
            &sA[(wr * 64 + mi * 16 + ln) * 64 + ((ks * 4 + quad) ^ (ln & 7)) * 8]);
#pragma unroll
      for (int ni = 0; ni < 4; ni++)
        bfr[ni] = *reinterpret_cast<const bhalf8*>(
            &sB[(wc * 64 + ni * 16 + ln) * 64 + ((ks * 4 + quad) ^ (ln & 7)) * 8]);
#pragma unroll
      for (int mi = 0; mi < 4; mi++)
#pragma unroll
        for (int ni = 0; ni < 4; ni++)
          acc[mi][ni] = MFMA16(af[mi], bfr[ni], acc[mi][ni]);
    }
    __syncthreads();
  }

  float bv[4];
#pragma unroll
  for (int ni = 0; ni < 4; ni++) bv[ni] = bias[n0 + wc * 64 + ni * 16 + ln];
#pragma unroll
  for (int mi = 0; mi < 4; mi++)
#pragma unroll
    for (int ni = 0; ni < 4; ni++)
#pragma unroll
      for (int r = 0; r < 4; r++) {
        const int row = m0 + wr * 64 + mi * 16 + quad * 4 + r;
        const int col = n0 + wc * 64 + ni * 16 + ln;
        of[(size_t)row * Cn + col] = acc[mi][ni][r] + bv[ni];
      }
}

// ---------------- flash attention v3: QBLK=128 (32 q-rows/wave), KVBLK=64.
// One dispatch covers 2 batches (512 blocks, 1D). 48KB LDS -> 3 blocks/CU.
// Each K/V fragment read feeds 2 MFMAs (mi-pair) -> per-q-row LDS read traffic
// halved vs QBLK=64 (round-9 PMC: LDS-pipe-bound).
// Pipeline per 64-K-tile: [vmcnt(4)+bar] QK^T -> softmax -> [vmcnt(0)+bar]
// stageK(t+1) -> P->sP (wave-private: lgkm only, NO barrier) -> PV ->
// [lgkm+bar] stageV(t+1). 3 barriers/iter.
__global__ __launch_bounds__(256, 3) void flash_attn2(const bhalf* __restrict__ qk,
                                                      const bhalf* __restrict__ vt,
                                                      bhalf* __restrict__ yb) {
  __shared__ __align__(16) bhalf sK[64 * 128];    // K tile [kpos][d], chunk^(row&15)
  __shared__ __align__(16) bhalf sVT[128 * 64];   // V^T tile [d][kpos], chunk^(row&7)
  __shared__ __align__(16) bhalf sP[128 * 64];    // P tile [qrow][kpos], chunk^(row&7)
  const int tid = threadIdx.x;
  const int lane = tid & 63, wv = tid >> 6;       // wave owns q-rows [wv*32, wv*32+32)
  const int ln = lane & 15, quad = lane >> 4;
  const int rl = lane >> 4, cl = lane & 15;       // K-staging row-in-group / chunk
  const int l = blockIdx.x;                        // 0..511 (2 batches)
  const int b = l >> 8;                            // 256 blocks per batch
  const int l5 = l & 255;
  const int h = ((l5 & 7) << 1) | ((l5 >> 3) & 1);
  const int t0q = (l5 >> 4) * 128;                 // 16 q-tiles of 128
  const bhalf* Qb  = qk + (size_t)b * 2 * SLOT;
  const bhalf* Kb  = Qb + SLOT;
  const bhalf* VTb = vt + (size_t)b * SLOT;
  bhalf* Ob        = yb + (size_t)b * SLOT;
  const size_t hb = (size_t)h * Tn * Dh;          // == h*Dh*Tn for vt
  constexpr float kSc = 0.08838834764831845f * 1.4426950408889634f;  // 1/sqrt(Dh)*log2e

  bhalf8 qf[2][4];                                 // [mi][kd]: rows wv*32+mi*16+ln
#pragma unroll
  for (int mi = 0; mi < 2; mi++)
#pragma unroll
    for (int kd = 0; kd < 4; kd++)
      qf[mi][kd] = *reinterpret_cast<const bhalf8*>(
          Qb + hb + (size_t)(t0q + wv * 32 + mi * 16 + ln) * Dh + kd * 32 + quad * 8);

  const floatx4 fzero = {0.f, 0.f, 0.f, 0.f};
  floatx4 oAcc[2][8];
#pragma unroll
  for (int mi = 0; mi < 2; mi++)
#pragma unroll
    for (int di = 0; di < 8; di++) oAcc[mi][di] = fzero;
  float lrow[2][4] = {{0.f, 0.f, 0.f, 0.f}, {0.f, 0.f, 0.f, 0.f}};

  // 4 gload16 calls each (vmcnt counts: 4 per stage)
  auto stageK = [&](int t0k) {
#pragma unroll
    for (int j = 0; j < 4; j++) {
      const int rloc = wv * 16 + j * 4 + rl;      // 64 rows over 4 waves
      const int c = cl ^ (rloc & 15);
      gload16(Kb + hb + (size_t)(t0k + rloc) * Dh + c * 8, sK + (wv * 16 + j * 4) * 128);
    }
  };
  auto stageV = [&](int t0k) {
#pragma unroll
    for (int j = 0; j < 4; j++) {
      const int dloc = j * 32 + wv * 8 + (lane >> 3);  // 128 d-rows (64 B rows)
      const int c = (lane & 7) ^ (dloc & 7);
      gload16(VTb + hb + (size_t)dloc * Tn + t0k + c * 8, sVT + (j * 32 + wv * 8) * 64);
    }
  };

  // prologue: issue K(0) then V(0); clobber pins VMEM issue order (vmcnt counting)
  stageK(0);
  asm volatile("" ::: "memory");
  stageV(0);

  for (int t0k = 0; t0k < Tn; t0k += 64) {
    // K(t) ready: 4 newest outstanding are V(t) (iter 0 also drains older qf loads)
    asm volatile("s_waitcnt vmcnt(4)" ::: "memory");
    __builtin_amdgcn_s_barrier();
    asm volatile("" ::: "memory");

    // S = Q K^T (contract over d); each bfr feeds both mi
    floatx4 sAcc[2][4];
#pragma unroll
    for (int mi = 0; mi < 2; mi++)
#pragma unroll
      for (int ni = 0; ni < 4; ni++) sAcc[mi][ni] = fzero;
    __builtin_amdgcn_s_setprio(1);
#pragma unroll
    for (int kd = 0; kd < 4; kd++) {
#pragma unroll
      for (int ni = 0; ni < 4; ni++) {
        const bhalf8 bfr = *reinterpret_cast<const bhalf8*>(
            &sK[(ni * 16 + ln) * 128 + ((kd * 4 + quad) ^ ln) * 8]);
        sAcc[0][ni] = MFMA16(qf[0][kd], bfr, sAcc[0][ni]);
        sAcc[1][ni] = MFMA16(qf[1][kd], bfr, sAcc[1][ni]);
      }
    }
    __builtin_amdgcn_s_setprio(0);

    // unnormalized softmax: p = exp2(s*kSc), l += row-sum(p)
#pragma unroll
    for (int mi = 0; mi < 2; mi++)
#pragma unroll
      for (int r = 0; r < 4; r++) {
        float rs = 0.f;
#pragma unroll
        for (int ni = 0; ni < 4; ni++) {
          const float p = exp2f(sAcc[mi][ni][r] * kSc);
          sAcc[mi][ni][r] = p;
          rs += p;
        }
        rs += __shfl_xor(rs, 1);
        rs += __shfl_xor(rs, 2);
        rs += __shfl_xor(rs, 4);
        rs += __shfl_xor(rs, 8);
        lrow[mi][r] += rs;
      }

    // V(t) ready; all waves past QK^T reads of sK -> safe to refill sK
    asm volatile("s_waitcnt vmcnt(0)" ::: "memory");
    __builtin_amdgcn_s_barrier();
    asm volatile("" ::: "memory");
    if (t0k + 64 < Tn) stageK(t0k + 64);   // overlaps P-write + PV

    // P (C/D layout) -> sP [qrow][kpos], chunk^(qrow&7). sP rows are WAVE-PRIVATE
    // (write rows wv*32+mi*16+quad*4+r; read rows wv*32+mi*16+ln) -> lgkm only.
#pragma unroll
    for (int mi = 0; mi < 2; mi++)
#pragma unroll
      for (int ni = 0; ni < 4; ni++)
#pragma unroll
        for (int r = 0; r < 4; r++) {
          const int qrow = wv * 32 + mi * 16 + quad * 4 + r;
          const int kcol = ni * 16 + ln;
          sP[qrow * 64 + (((kcol >> 3) ^ (qrow & 7)) * 8) + (kcol & 7)] =
              (bhalf)sAcc[mi][ni][r];
        }
    asm volatile("s_waitcnt lgkmcnt(0)" ::: "memory");  // own ds_writes -> own reads

    // O += P V (contract over kpos); each bv feeds both mi
    __builtin_amdgcn_s_setprio(1);
#pragma unroll
    for (int kt = 0; kt < 2; kt++) {
      bhalf8 ap[2];
#pragma unroll
      for (int mi = 0; mi < 2; mi++)
        ap[mi] = *reinterpret_cast<const bhalf8*>(
            &sP[(wv * 32 + mi * 16 + ln) * 64 + ((kt * 4 + quad) ^ (ln & 7)) * 8]);
#pragma unroll
      for (int di = 0; di < 8; di++) {
        const bhalf8 bv = *reinterpret_cast<const bhalf8*>(
            &sVT[(di * 16 + ln) * 64 + ((kt * 4 + quad) ^ (ln & 7)) * 8]);
        oAcc[0][di] = MFMA16(ap[0], bv, oAcc[0][di]);
        oAcc[1][di] = MFMA16(ap[1], bv, oAcc[1][di]);
      }
    }
    __builtin_amdgcn_s_setprio(0);

    asm volatile("s_waitcnt lgkmcnt(0)" ::: "memory");
    __builtin_amdgcn_s_barrier();
    asm volatile("" ::: "memory");
    if (t0k + 64 < Tn) stageV(t0k + 64);   // overlaps next QK^T + softmax
  }

  // epilogue: O / l -> y [T,C]
#pragma unroll
  for (int mi = 0; mi < 2; mi++)
#pragma unroll
    for (int r = 0; r < 4; r++) {
      const float inv = 1.0f / lrow[mi][r];
      const int t = t0q + wv * 32 + mi * 16 + quad * 4 + r;
      const size_t rowb = (size_t)t * Cn + h * Dh;
#pragma unroll
      for (int di = 0; di < 8; di++)
        Ob[rowb + di * 16 + ln] = (bhalf)(oAcc[mi][di][r] * inv);
    }
}

extern "C" void kernel_launch(void* const* d_in, const int* in_sizes, int n_in,
                              void* d_out, int out_size, void* d_ws, size_t ws_size,
                              hipStream_t stream) {
  const float* x      = (const float*)d_in[0];
  const float* W_attn = (const float*)d_in[1];
  const float* b_attn = (const float*)d_in[2];
  const float* W_proj = (const float*)d_in[3];
  const float* b_proj = (const float*)d_in[4];
  float* out = (float*)d_out;
  bhalf* ws  = (bhalf*)d_ws;

  // slots (1 SLOT each):
  //   phase QKV: xb @ 0-3, wtQK @ 4-5 -> qk in d_out (xb dead after gemm_qk)
  //   phase V  : wtV @ 0, vt @ 2-5 (fp32-A gemm, reads x directly)
  //   phase FA : dispatch 0 = batches {0,1}: reads vt 2,3 writes y 0,1 (no overlap);
  //              dispatch 1 = batches {2,3}: reads vt 4,5 writes y 2,3 (overwrites
  //              vt 2,3 -- ordered after dispatch 0 by the stream boundary)
  //   phase PRJ: wtP @ 4, proj reads y@0-3 contiguous, writes d_out (qk dead)
  bhalf* xb   = ws;                 // [8192][2048] bf16
  bhalf* wtQK = ws + 4 * SLOT;      // [4096][2048]
  bhalf* wtV  = ws;                 // slot 0 (xb dead)
  bhalf* vt   = ws + 2 * SLOT;      // [B,H,Dh,T]
  bhalf* y    = ws;                 // y_b at slot b (contiguous [8192][2048])
  bhalf* wtP  = ws + 4 * SLOT;
  bhalf* qk   = (bhalf*)d_out;      // [q0,k0,q1,k1,...]; dead before proj

  // x -> bf16 once (removes fp32 staging from the big q,k GEMM)
  cvt_x<<<8192, 256, 0, stream>>>(x, xb);

  // q,k projection (one dispatch, N=4096), all-bf16 A
  transpose_cvt<<<dim3(64, 32), 256, 0, stream>>>(W_attn, wtQK, 3 * Cn, Kdim, 0);
  gemm_qk<<<dim3(32, 64), 256, 0, stream>>>(xb, wtQK, b_attn, qk, qk + SLOT);

  // v projection -> v^T (fp32-A path; xb slots 0-3 now dead, wtV reuses slot 0)
  transpose_cvt<<<dim3(32, 32), 256, 0, stream>>>(W_attn, wtV, 3 * Cn, Kdim, 2 * Cn);
  gemm_xa<2><<<dim3(16, 64), 256, 0, stream>>>(x, wtV, b_attn + 2 * Cn, vt, nullptr);

  // flash: 2 dispatches of 512 blocks (2 batches each) -- race-free slot reuse
  flash_attn2<<<512, 256, 0, stream>>>(qk, vt, y);
  flash_attn2<<<512, 256, 0, stream>>>(qk + 4 * SLOT, vt + 2 * SLOT, y + 2 * SLOT);

  // output projection (batched; overwrites q,k scratch in d_out)
  transpose_cvt<<<dim3(32, 32), 256, 0, stream>>>(W_proj, wtP, Kdim, Kdim, 0);
  gemm_proj<<<dim3(16, 64), 256, 0, stream>>>(y, wtP, b_proj, out);
}

// Round 13
// 701.436 us; speedup vs baseline: 1.9934x; 1.9934x over previous
//
#include <hip/hip_runtime.h>

// MultiHeadAttention: fp32 in/out, bf16 MFMA compute. B=4 T=2048 C=2048 H=16 Dh=128.
// ws = 6 SLOT = 50.33 MB (SLOT = 4.19M bf16 = 8.39 MB).
// Slot chain: cvt_x -> xb[0-3], wtQK[4-5] -> gemm_qk (bf16 A) -> qk in d_out.
// Then (xb dead): wtV[0], vt[2-5] via fp32-A gemm_xa<2>; flash (2 dispatches,
// batches {0,1} then {2,3} -- dispatch boundary orders y-writes vs vt-reads):
// vt(2+b) -> y[b]; wtP[4]; proj reads y[0-3] contiguous.
// Flash v3b: QBLK=128 (32 q-rows/wave), KVBLK=64, 512 blocks/dispatch, 48KB LDS.
// (256,2) launch bounds: R11's (256,3) capped VGPR at ~170-with-AGPR-alias ->
// spilled ~80 regs -> 260MB scratch WRITE_SIZE, 475us. (256,2) = no spill.

using bhalf  = __bf16;
using bhalf8 = __attribute__((ext_vector_type(8))) __bf16;   // MFMA A/B frag (4 VGPRs)
using floatx4 = __attribute__((ext_vector_type(4))) float;   // MFMA C/D frag

#define MFMA16(A, B, C) __builtin_amdgcn_mfma_f32_16x16x32_bf16(A, B, C, 0, 0, 0)

__device__ __forceinline__ void gload16(const void* g, void* l) {
  // async global->LDS, 16B/lane; LDS dest = wave-uniform base + lane*16B
  __builtin_amdgcn_global_load_lds(
      (const __attribute__((address_space(1))) unsigned int*)g,
      (__attribute__((address_space(3))) unsigned int*)l, 16, 0, 0);
}

constexpr int Bn = 4, Tn = 2048, Cn = 2048, Hn = 16, Dh = 128;
constexpr int Kdim = Cn;
constexpr size_t SLOT = (size_t)Hn * Tn * Dh;  // 4,194,304 elems (8.39 MB bf16)

// ---------------- x fp32 -> bf16 (one pass; [8192][2048])
__global__ __launch_bounds__(256) void cvt_x(const float* __restrict__ in,
                                             bhalf* __restrict__ out) {
  const size_t i = ((size_t)blockIdx.x * 256 + threadIdx.x) * 8;
  const float4 a = *reinterpret_cast<const float4*>(in + i);
  const float4 b = *reinterpret_cast<const float4*>(in + i + 4);
  bhalf8 v;
  v[0] = (bhalf)a.x; v[1] = (bhalf)a.y; v[2] = (bhalf)a.z; v[3] = (bhalf)a.w;
  v[4] = (bhalf)b.x; v[5] = (bhalf)b.y; v[6] = (bhalf)b.z; v[7] = (bhalf)b.w;
  *reinterpret_cast<bhalf8*>(out + i) = v;
}

// ---------------- fp32 transpose+convert: out[c][r] = (bhalf)in[r*ldin + coff + c]
__global__ __launch_bounds__(256) void transpose_cvt(const float* __restrict__ in,
                                                     bhalf* __restrict__ out,
                                                     int ldin, int ldout, int coff) {
  __shared__ unsigned short tile[64][65];
  const int c0 = blockIdx.x * 64, r0 = blockIdx.y * 64;
  const int tx = threadIdx.x & 15, ty = threadIdx.x >> 4;
#pragma unroll
  for (int i = 0; i < 4; i++) {
    const int r = ty + i * 16;
    const float4 u = *reinterpret_cast<const float4*>(in + (size_t)(r0 + r) * ldin + coff + c0 + tx * 4);
    tile[r][tx * 4 + 0] = __builtin_bit_cast(unsigned short, (bhalf)u.x);
    tile[r][tx * 4 + 1] = __builtin_bit_cast(unsigned short, (bhalf)u.y);
    tile[r][tx * 4 + 2] = __builtin_bit_cast(unsigned short, (bhalf)u.z);
    tile[r][tx * 4 + 3] = __builtin_bit_cast(unsigned short, (bhalf)u.w);
  }
  __syncthreads();
#pragma unroll
  for (int i = 0; i < 4; i++) {
    const int c = ty + i * 16;
    ushort4 u;
    u.x = tile[tx * 4 + 0][c]; u.y = tile[tx * 4 + 1][c];
    u.z = tile[tx * 4 + 2][c]; u.w = tile[tx * 4 + 3][c];
    *reinterpret_cast<ushort4*>((unsigned short*)out + (size_t)(c0 + c) * ldout + r0 + tx * 4) = u;
  }
}

// ---------------- q,k GEMM, all-bf16: A = xb [8192][2048], Bt = W^T [4096][2048].
// 128x128x(BK=64), swizzled LDS. (256,4): R11 non-flash total ~448us vs R9's 476
// with (256,3) -> keep (256,4).
__global__ __launch_bounds__(256, 4) void gemm_qk(const bhalf* __restrict__ A,
                                                  const bhalf* __restrict__ Bt,
                                                  const float* __restrict__ bias,
                                                  bhalf* __restrict__ oq,
                                                  bhalf* __restrict__ ok) {
  __shared__ __align__(16) bhalf sA[128 * 64];   // 16 KB, 16B chunk c at c^(row&7)
  __shared__ __align__(16) bhalf sB[128 * 64];   // 16 KB
  const int tid = threadIdx.x;
  const int lane = tid & 63, wv = tid >> 6;
  const int ln = lane & 15, quad = lane >> 4;
  const int wr = wv >> 1, wc = wv & 1;
  const int m0 = blockIdx.y * 128, n0 = blockIdx.x * 128;

  const floatx4 fzero = {0.f, 0.f, 0.f, 0.f};
  floatx4 acc[4][4];
#pragma unroll
  for (int i = 0; i < 4; i++)
#pragma unroll
    for (int j = 0; j < 4; j++) acc[i][j] = fzero;

  const int schunk = (lane & 7) ^ ((lane >> 3) & 7);
  const bhalf* aStage = A + (size_t)(m0 + wv * 32 + (lane >> 3)) * Kdim + schunk * 8;
  const bhalf* bStage = Bt + (size_t)(n0 + wv * 32 + (lane >> 3)) * Kdim + schunk * 8;
  bhalf* sAw = &sA[(wv * 32) * 64];
  bhalf* sBw = &sB[(wv * 32) * 64];

  for (int k0 = 0; k0 < Kdim; k0 += 64) {
#pragma unroll
    for (int j = 0; j < 4; j++) gload16(aStage + (size_t)j * 8 * Kdim + k0, sAw + j * 8 * 64);
#pragma unroll
    for (int j = 0; j < 4; j++) gload16(bStage + (size_t)j * 8 * Kdim + k0, sBw + j * 8 * 64);
    __syncthreads();
#pragma unroll
    for (int ks = 0; ks < 2; ks++) {
      bhalf8 af[4], bfr[4];
#pragma unroll
      for (int mi = 0; mi < 4; mi++)
        af[mi] = *reinterpret_cast<const bhalf8*>(
            &sA[(wr * 64 + mi * 16 + ln) * 64 + ((ks * 4 + quad) ^ (ln & 7)) * 8]);
#pragma unroll
      for (int ni = 0; ni < 4; ni++)
        bfr[ni] = *reinterpret_cast<const bhalf8*>(
            &sB[(wc * 64 + ni * 16 + ln) * 64 + ((ks * 4 + quad) ^ (ln & 7)) * 8]);
#pragma unroll
      for (int mi = 0; mi < 4; mi++)
#pragma unroll
        for (int ni = 0; ni < 4; ni++)
          acc[mi][ni] = MFMA16(af[mi], bfr[ni], acc[mi][ni]);
    }
    __syncthreads();
  }

  const int b = m0 >> 11, t0 = m0 & 2047;
  const int which = n0 >> 11;             // 0: q, 1: k
  const int h = (n0 & 2047) >> 7;
  bhalf* op = which == 0 ? oq : ok;
  float bv[4];
#pragma unroll
  for (int ni = 0; ni < 4; ni++) bv[ni] = bias[n0 + wc * 64 + ni * 16 + ln];
  const size_t base = (size_t)b * (2 * SLOT) + ((size_t)h * Tn + t0) * Dh;
#pragma unroll
  for (int mi = 0; mi < 4; mi++)
#pragma unroll
    for (int ni = 0; ni < 4; ni++)
#pragma unroll
      for (int r = 0; r < 4; r++) {
        const int t = wr * 64 + mi * 16 + quad * 4 + r;  // C/D: row=quad*4+reg
        const int d = wc * 64 + ni * 16 + ln;            // C/D: col=lane&15
        op[base + (size_t)t * Dh + d] = (bhalf)(acc[mi][ni][r] + bv[ni]);
      }
}

// ---------------- v GEMM: A = x fp32 (staged fp32, cvt in frag load),
// Bt = W_v^T bf16 [2048][2048]. Swapped operands -> v^T [B,H,Dh,T] (+bias over d).
template <int MODE>
__global__ __launch_bounds__(256, 3) void gemm_xa(const float* __restrict__ A,
                                                  const bhalf* __restrict__ Bt,
                                                  const float* __restrict__ bias,
                                                  bhalf* __restrict__ oq,
                                                  bhalf* __restrict__ ok) {
  __shared__ __align__(16) float sA[128 * 64];   // 32 KB, 16B chunk c at c^(row&15)
  __shared__ __align__(16) bhalf sB[128 * 64];   // 16 KB, 16B chunk c at c^(row&7)
  const int tid = threadIdx.x;
  const int lane = tid & 63, wv = tid >> 6;
  const int ln = lane & 15, quad = lane >> 4;
  const int wr = wv >> 1, wc = wv & 1;  // 2x2 wave grid, 64x64 per wave
  const int m0 = blockIdx.y * 128, n0 = blockIdx.x * 128;

  const floatx4 fzero = {0.f, 0.f, 0.f, 0.f};
  floatx4 acc[4][4];
#pragma unroll
  for (int i = 0; i < 4; i++)
#pragma unroll
    for (int j = 0; j < 4; j++) acc[i][j] = fzero;

  const int schunkB = (lane & 7) ^ ((lane >> 3) & 7);
  const bhalf* bStage = Bt + (size_t)(n0 + wv * 32 + (lane >> 3)) * Kdim + schunkB * 8;
  bhalf* sBw = &sB[(wv * 32) * 64];
  const int rA = lane >> 4, cA = lane & 15;
  float* sAw = &sA[(wv * 32) * 64];

  for (int k0 = 0; k0 < Kdim; k0 += 64) {
#pragma unroll
    for (int j = 0; j < 8; j++) {
      const int rloc = j * 4 + rA;
      const int gc = cA ^ (rloc & 15);
      gload16(A + (size_t)(m0 + wv * 32 + rloc) * Kdim + k0 + gc * 4, sAw + (j * 4) * 64);
    }
#pragma unroll
    for (int j = 0; j < 4; j++) gload16(bStage + (size_t)j * 8 * Kdim + k0, sBw + j * 8 * 64);
    __syncthreads();
#pragma unroll
    for (int ks = 0; ks < 2; ks++) {
      bhalf8 af[4], bfr[4];
#pragma unroll
      for (int mi = 0; mi < 4; mi++) {
        const int row = wr * 64 + mi * 16 + ln;   // row&15 == ln
        const int c0c = ks * 8 + quad * 2;
        const float4 lo = *reinterpret_cast<const float4*>(&sA[row * 64 + ((c0c ^ ln) * 4)]);
        const float4 hi = *reinterpret_cast<const float4*>(&sA[row * 64 + (((c0c + 1) ^ ln) * 4)]);
        bhalf8 t;
        t[0] = (bhalf)lo.x; t[1] = (bhalf)lo.y; t[2] = (bhalf)lo.z; t[3] = (bhalf)lo.w;
        t[4] = (bhalf)hi.x; t[5] = (bhalf)hi.y; t[6] = (bhalf)hi.z; t[7] = (bhalf)hi.w;
        af[mi] = t;
      }
#pragma unroll
      for (int ni = 0; ni < 4; ni++)
        bfr[ni] = *reinterpret_cast<const bhalf8*>(
            &sB[(wc * 64 + ni * 16 + ln) * 64 + ((ks * 4 + quad) ^ (ln & 7)) * 8]);
#pragma unroll
      for (int i = 0; i < 4; i++)
#pragma unroll
        for (int j = 0; j < 4; j++) {
          if (MODE == 2)
            acc[i][j] = MFMA16(bfr[i], af[j], acc[i][j]);  // D^T: acc[ni][mi]
          else
            acc[i][j] = MFMA16(af[i], bfr[j], acc[i][j]);  // D:   acc[mi][ni]
        }
    }
    __syncthreads();
  }

  const int b = m0 >> 11, t0 = m0 & 2047;
  if (MODE == 0) {
    const int which = n0 >> 11;             // 0: q, 1: k
    const int h = (n0 & 2047) >> 7;
    bhalf* op = which == 0 ? oq : ok;
    float bv[4];
#pragma unroll
    for (int ni = 0; ni < 4; ni++) bv[ni] = bias[n0 + wc * 64 + ni * 16 + ln];
    const size_t base = (size_t)b * (2 * SLOT) + ((size_t)h * Tn + t0) * Dh;
#pragma unroll
    for (int mi = 0; mi < 4; mi++)
#pragma unroll
      for (int ni = 0; ni < 4; ni++)
#pragma unroll
        for (int r = 0; r < 4; r++) {
          const int t = wr * 64 + mi * 16 + quad * 4 + r;  // C/D: row=quad*4+reg
          const int d = wc * 64 + ni * 16 + ln;            // C/D: col=lane&15
          op[base + (size_t)t * Dh + d] = (bhalf)(acc[mi][ni][r] + bv[ni]);
        }
  } else {  // MODE 2: acc[ni][mi]; D^T row = d, col = t
    const int h = n0 >> 7;
    const size_t base = (size_t)(b * Hn + h) * Dh * Tn;
#pragma unroll
    for (int ni = 0; ni < 4; ni++)
#pragma unroll
      for (int mi = 0; mi < 4; mi++)
#pragma unroll
        for (int r = 0; r < 4; r++) {
          const int d = wc * 64 + ni * 16 + quad * 4 + r;
          const int t = t0 + wr * 64 + mi * 16 + ln;
          oq[base + (size_t)d * Tn + t] = (bhalf)(acc[ni][mi][r] + bias[n0 + d]);
        }
  }
}

// ---------------- proj GEMM: A = y bf16 [8192][2048], Bt = W_proj^T, out fp32 (+bias)
__global__ __launch_bounds__(256, 3) void gemm_proj(const bhalf* __restrict__ A,
                                                    const bhalf* __restrict__ Bt,
                                                    const float* __restrict__ bias,
                                                    float* __restrict__ of) {
  __shared__ __align__(16) bhalf sA[128 * 64];
  __shared__ __align__(16) bhalf sB[128 * 64];
  const int tid = threadIdx.x;
  const int lane = tid & 63, wv = tid >> 6;
  const int ln = lane & 15, quad = lane >> 4;
  const int wr = wv >> 1, wc = wv & 1;
  const int m0 = blockIdx.y * 128, n0 = blockIdx.x * 128;

  const floatx4 fzero = {0.f, 0.f, 0.f, 0.f};
  floatx4 acc[4][4];
#pragma unroll
  for (int i = 0; i < 4; i++)
#pragma unroll
    for (int j = 0; j < 4; j++) acc[i][j] = fzero;

  const int schunk = (lane & 7) ^ ((lane >> 3) & 7);
  const bhalf* aStage = A + (size_t)(m0 + wv * 32 + (lane >> 3)) * Kdim + schunk * 8;
  const bhalf* bStage = Bt + (size_t)(n0 + wv * 32 + (lane >> 3)) * Kdim + schunk * 8;
  bhalf* sAw = &sA[(wv * 32) * 64];
  bhalf* sBw = &sB[(wv * 32) * 64];

  for (int k0 = 0; k0 < Kdim; k0 += 64) {
#pragma unroll
    for (int j = 0; j < 4; j++) gload16(aStage + (size_t)j * 8 * Kdim + k0, sAw + j * 8 * 64);
#pragma unroll
    for (int j = 0; j < 4; j++) gload16(bStage + (size_t)j * 8 * Kdim + k0, sBw + j * 8 * 64);
    __syncthreads();
#pragma unroll
    for (int ks = 0; ks < 2; ks++) {
      bhalf8 af[4], bfr[4];
#pragma unroll
      for (int mi = 0; mi < 4; mi++)
        af[mi] = *reinterpret_cast<const bhalf8*>(
            &sA[(wr * 64 + mi * 16 + ln) * 64 + ((ks * 4 + quad) ^ (ln & 7)) * 8]);
#pragma unroll
      for (int ni = 0; ni < 4; ni++)
        bfr[ni] = *reinterpret_cast<const bhalf8*>(
            &sB[(wc * 64 + ni * 16 + ln) * 64 + ((ks * 4 + quad) ^ (ln & 7)) * 8]);
#pragma unroll
      for (int mi = 0; mi < 4; mi++)
#pragma unroll
        for (int ni = 0; ni < 4; ni++)
          acc[mi][ni] = MFMA16(af[mi], bfr[ni], acc[mi][ni]);
    }
    __syncthreads();
  }

  float bv[4];
#pragma unroll
  for (int ni = 0; ni < 4; ni++) bv[ni] = bias[n0 + wc * 64 + ni * 16 + ln];
#pragma unroll
  for (int mi = 0; mi < 4; mi++)
#pragma unroll
    for (int ni = 0; ni < 4; ni++)
#pragma unroll
      for (int r = 0; r < 4; r++) {
        const int row = m0 + wr * 64 + mi * 16 + quad * 4 + r;
        const int col = n0 + wc * 64 + ni * 16 + ln;
        of[(size_t)row * Cn + col] = acc[mi][ni][r] + bv[ni];
      }
}

// ---------------- flash attention v3b: QBLK=128 (32 q-rows/wave), KVBLK=64.
// One dispatch covers 2 batches (512 blocks, 1D). 48KB LDS.
// (256,2): ~170 VGPR state fits with NO SPILL (R11's (256,3) spilled -> 260MB
// scratch writes, 475us). LDS still allows 3 blocks/CU if regalloc lands <=170.
// Each K/V fragment read feeds 2 MFMAs (mi-pair) -> per-q-row LDS read traffic
// halved vs QBLK=64 (round-9 PMC: LDS-pipe-bound).
// Pipeline per 64-K-tile: [vmcnt(4)+bar] QK^T -> softmax -> [vmcnt(0)+bar]
// stageK(t+1) -> P->sP (wave-private: lgkm only, NO barrier) -> PV ->
// [lgkm+bar] stageV(t+1). 3 barriers/iter.
__global__ __launch_bounds__(256, 2) void flash_attn2(const bhalf* __restrict__ qk,
                                                      const bhalf* __restrict__ vt,
                                                      bhalf* __restrict__ yb) {
  __shared__ __align__(16) bhalf sK[64 * 128];    // K tile [kpos][d], chunk^(row&15)
  __shared__ __align__(16) bhalf sVT[128 * 64];   // V^T tile [d][kpos], chunk^(row&7)
  __shared__ __align__(16) bhalf sP[128 * 64];    // P tile [qrow][kpos], chunk^(row&7)
  const int tid = threadIdx.x;
  const int lane = tid & 63, wv = tid >> 6;       // wave owns q-rows [wv*32, wv*32+32)
  const int ln = lane & 15, quad = lane >> 4;
  const int rl = lane >> 4, cl = lane & 15;       // K-staging row-in-group / chunk
  const int l = blockIdx.x;                        // 0..511 (2 batches)
  const int b = l >> 8;                            // 256 blocks per batch
  const int l5 = l & 255;
  const int h = ((l5 & 7) << 1) | ((l5 >> 3) & 1);
  const int t0q = (l5 >> 4) * 128;                 // 16 q-tiles of 128
  const bhalf* Qb  = qk + (size_t)b * 2 * SLOT;
  const bhalf* Kb  = Qb + SLOT;
  const bhalf* VTb = vt + (size_t)b * SLOT;
  bhalf* Ob        = yb + (size_t)b * SLOT;
  const size_t hb = (size_t)h * Tn * Dh;          // == h*Dh*Tn for vt
  constexpr float kSc = 0.08838834764831845f * 1.4426950408889634f;  // 1/sqrt(Dh)*log2e

  bhalf8 qf[2][4];                                 // [mi][kd]: rows wv*32+mi*16+ln
#pragma unroll
  for (int mi = 0; mi < 2; mi++)
#pragma unroll
    for (int kd = 0; kd < 4; kd++)
      qf[mi][kd] = *reinterpret_cast<const bhalf8*>(
          Qb + hb + (size_t)(t0q + wv * 32 + mi * 16 + ln) * Dh + kd * 32 + quad * 8);

  const floatx4 fzero = {0.f, 0.f, 0.f, 0.f};
  floatx4 oAcc[2][8];
#pragma unroll
  for (int mi = 0; mi < 2; mi++)
#pragma unroll
    for (int di = 0; di < 8; di++) oAcc[mi][di] = fzero;
  float lrow[2][4] = {{0.f, 0.f, 0.f, 0.f}, {0.f, 0.f, 0.f, 0.f}};

  // 4 gload16 calls each (vmcnt counts: 4 per stage)
  auto stageK = [&](int t0k) {
#pragma unroll
    for (int j = 0; j < 4; j++) {
      const int rloc = wv * 16 + j * 4 + rl;      // 64 rows over 4 waves
      const int c = cl ^ (rloc & 15);
      gload16(Kb + hb + (size_t)(t0k + rloc) * Dh + c * 8, sK + (wv * 16 + j * 4) * 128);
    }
  };
  auto stageV = [&](int t0k) {
#pragma unroll
    for (int j = 0; j < 4; j++) {
      const int dloc = j * 32 + wv * 8 + (lane >> 3);  // 128 d-rows (64 B rows)
      const int c = (lane & 7) ^ (dloc & 7);
      gload16(VTb + hb + (size_t)dloc * Tn + t0k + c * 8, sVT + (j * 32 + wv * 8) * 64);
    }
  };

  // prologue: issue K(0) then V(0); clobber pins VMEM issue order (vmcnt counting)
  stageK(0);
  asm volatile("" ::: "memory");
  stageV(0);

  for (int t0k = 0; t0k < Tn; t0k += 64) {
    // K(t) ready: 4 newest outstanding are V(t) (iter 0 also drains older qf loads)
    asm volatile("s_waitcnt vmcnt(4)" ::: "memory");
    __builtin_amdgcn_s_barrier();
    asm volatile("" ::: "memory");

    // S = Q K^T (contract over d); each bfr feeds both mi
    floatx4 sAcc[2][4];
#pragma unroll
    for (int mi = 0; mi < 2; mi++)
#pragma unroll
      for (int ni = 0; ni < 4; ni++) sAcc[mi][ni] = fzero;
    __builtin_amdgcn_s_setprio(1);
#pragma unroll
    for (int kd = 0; kd < 4; kd++) {
#pragma unroll
      for (int ni = 0; ni < 4; ni++) {
        const bhalf8 bfr = *reinterpret_cast<const bhalf8*>(
            &sK[(ni * 16 + ln) * 128 + ((kd * 4 + quad) ^ ln) * 8]);
        sAcc[0][ni] = MFMA16(qf[0][kd], bfr, sAcc[0][ni]);
        sAcc[1][ni] = MFMA16(qf[1][kd], bfr, sAcc[1][ni]);
      }
    }
    __builtin_amdgcn_s_setprio(0);

    // unnormalized softmax: p = exp2(s*kSc), l += row-sum(p)
#pragma unroll
    for (int mi = 0; mi < 2; mi++)
#pragma unroll
      for (int r = 0; r < 4; r++) {
        float rs = 0.f;
#pragma unroll
        for (int ni = 0; ni < 4; ni++) {
          const float p = exp2f(sAcc[mi][ni][r] * kSc);
          sAcc[mi][ni][r] = p;
          rs += p;
        }
        rs += __shfl_xor(rs, 1);
        rs += __shfl_xor(rs, 2);
        rs += __shfl_xor(rs, 4);
        rs += __shfl_xor(rs, 8);
        lrow[mi][r] += rs;
      }

    // V(t) ready; all waves past QK^T reads of sK -> safe to refill sK
    asm volatile("s_waitcnt vmcnt(0)" ::: "memory");
    __builtin_amdgcn_s_barrier();
    asm volatile("" ::: "memory");
    if (t0k + 64 < Tn) stageK(t0k + 64);   // overlaps P-write + PV

    // P (C/D layout) -> sP [qrow][kpos], chunk^(qrow&7). sP rows are WAVE-PRIVATE
    // (write rows wv*32+mi*16+quad*4+r; read rows wv*32+mi*16+ln) -> lgkm only.
#pragma unroll
    for (int mi = 0; mi < 2; mi++)
#pragma unroll
      for (int ni = 0; ni < 4; ni++)
#pragma unroll
        for (int r = 0; r < 4; r++) {
          const int qrow = wv * 32 + mi * 16 + quad * 4 + r;
          const int kcol = ni * 16 + ln;
          sP[qrow * 64 + (((kcol >> 3) ^ (qrow & 7)) * 8) + (kcol & 7)] =
              (bhalf)sAcc[mi][ni][r];
        }
    asm volatile("s_waitcnt lgkmcnt(0)" ::: "memory");  // own ds_writes -> own reads

    // O += P V (contract over kpos); each bv feeds both mi
    __builtin_amdgcn_s_setprio(1);
#pragma unroll
    for (int kt = 0; kt < 2; kt++) {
      bhalf8 ap[2];
#pragma unroll
      for (int mi = 0; mi < 2; mi++)
        ap[mi] = *reinterpret_cast<const bhalf8*>(
            &sP[(wv * 32 + mi * 16 + ln) * 64 + ((kt * 4 + quad) ^ (ln & 7)) * 8]);
#pragma unroll
      for (int di = 0; di < 8; di++) {
        const bhalf8 bv = *reinterpret_cast<const bhalf8*>(
            &sVT[(di * 16 + ln) * 64 + ((kt * 4 + quad) ^ (ln & 7)) * 8]);
        oAcc[0][di] = MFMA16(ap[0], bv, oAcc[0][di]);
        oAcc[1][di] = MFMA16(ap[1], bv, oAcc[1][di]);
      }
    }
    __builtin_amdgcn_s_setprio(0);

    asm volatile("s_waitcnt lgkmcnt(0)" ::: "memory");
    __builtin_amdgcn_s_barrier();
    asm volatile("" ::: "memory");
    if (t0k + 64 < Tn) stageV(t0k + 64);   // overlaps next QK^T + softmax
  }

  // epilogue: O / l -> y [T,C]
#pragma unroll
  for (int mi = 0; mi < 2; mi++)
#pragma unroll
    for (int r = 0; r < 4; r++) {
      const float inv = 1.0f / lrow[mi][r];
      const int t = t0q + wv * 32 + mi * 16 + quad * 4 + r;
      const size_t rowb = (size_t)t * Cn + h * Dh;
#pragma unroll
      for (int di = 0; di < 8; di++)
        Ob[rowb + di * 16 + ln] = (bhalf)(oAcc[mi][di][r] * inv);
    }
}

extern "C" void kernel_launch(void* const* d_in, const int* in_sizes, int n_in,
                              void* d_out, int out_size, void* d_ws, size_t ws_size,
                              hipStream_t stream) {
  const float* x      = (const float*)d_in[0];
  const float* W_attn = (const float*)d_in[1];
  const float* b_attn = (const float*)d_in[2];
  const float* W_proj = (const float*)d_in[3];
  const float* b_proj = (const float*)d_in[4];
  float* out = (float*)d_out;
  bhalf* ws  = (bhalf*)d_ws;

  // slots (1 SLOT each):
  //   phase QKV: xb @ 0-3, wtQK @ 4-5 -> qk in d_out (xb dead after gemm_qk)
  //   phase V  : wtV @ 0, vt @ 2-5 (fp32-A gemm, reads x directly)
  //   phase FA : dispatch 0 = batches {0,1}: reads vt 2,3 writes y 0,1 (no overlap);
  //              dispatch 1 = batches {2,3}: reads vt 4,5 writes y 2,3 (overwrites
  //              vt 2,3 -- ordered after dispatch 0 by the stream boundary)
  //   phase PRJ: wtP @ 4, proj reads y@0-3 contiguous, writes d_out (qk dead)
  bhalf* xb   = ws;                 // [8192][2048] bf16
  bhalf* wtQK = ws + 4 * SLOT;      // [4096][2048]
  bhalf* wtV  = ws;                 // slot 0 (xb dead)
  bhalf* vt   = ws + 2 * SLOT;      // [B,H,Dh,T]
  bhalf* y    = ws;                 // y_b at slot b (contiguous [8192][2048])
  bhalf* wtP  = ws + 4 * SLOT;
  bhalf* qk   = (bhalf*)d_out;      // [q0,k0,q1,k1,...]; dead before proj

  // x -> bf16 once (removes fp32 staging from the big q,k GEMM)
  cvt_x<<<8192, 256, 0, stream>>>(x, xb);

  // q,k projection (one dispatch, N=4096), all-bf16 A
  transpose_cvt<<<dim3(64, 32), 256, 0, stream>>>(W_attn, wtQK, 3 * Cn, Kdim, 0);
  gemm_qk<<<dim3(32, 64), 256, 0, stream>>>(xb, wtQK, b_attn, qk, qk + SLOT);

  // v projection -> v^T (fp32-A path; xb slots 0-3 now dead, wtV reuses slot 0)
  transpose_cvt<<<dim3(32, 32), 256, 0, stream>>>(W_attn, wtV, 3 * Cn, Kdim, 2 * Cn);
  gemm_xa<2><<<dim3(16, 64), 256, 0, stream>>>(x, wtV, b_attn + 2 * Cn, vt, nullptr);

  // flash: 2 dispatches of 512 blocks (2 batches each) -- race-free slot reuse
  flash_attn2<<<512, 256, 0, stream>>>(qk, vt, y);
  flash_attn2<<<512, 256, 0, stream>>>(qk + 4 * SLOT, vt + 2 * SLOT, y + 2 * SLOT);

  // output projection (batched; overwrites q,k scratch in d_out)
  transpose_cvt<<<dim3(32, 32), 256, 0, stream>>>(W_proj, wtP, Kdim, Kdim, 0);
  gemm_proj<<<dim3(16, 64), 256, 0, stream>>>(y, wtP, b_proj, out);
}

// Round 15
// 661.105 us; speedup vs baseline: 2.1150x; 1.0610x over previous
//
#include <hip/hip_runtime.h>

// MultiHeadAttention: fp32 in/out, bf16 MFMA compute. B=4 T=2048 C=2048 H=16 Dh=128.
// ws = 6 SLOT = 50.33 MB (SLOT = 4.19M bf16 = 8.39 MB).
// Slot chain: cvt_x -> xb[0-3], wtQK[4-5] -> gemm_qk (bf16 A, q pre-scaled by
// 1/sqrt(Dh)*log2e) -> qk in d_out. Then: wtV[0], vt[2-5]; flash (2 dispatches,
// batches {0,1} then {2,3}); wtP[4]; proj reads y[0-3].
// Flash v3c: QBLK=128, KVBLK=64, (256,2) no-spill. R13 PMC: MFMA 22% VALU 38%
// invariant across 3 variants -> serial per-iter chain bound. This round:
// (1) rowsum shfl butterfly deferred to epilogue (-32 DS/iter + chain),
// (2) kSc folded into q (-32 vmul/iter), (3) P-write moved before V-wait
// barrier (overlaps HBM latency). Sync skeleton unchanged.

using bhalf  = __bf16;
using bhalf8 = __attribute__((ext_vector_type(8))) __bf16;   // MFMA A/B frag (4 VGPRs)
using floatx4 = __attribute__((ext_vector_type(4))) float;   // MFMA C/D frag

#define MFMA16(A, B, C) __builtin_amdgcn_mfma_f32_16x16x32_bf16(A, B, C, 0, 0, 0)

__device__ __forceinline__ void gload16(const void* g, void* l) {
  // async global->LDS, 16B/lane; LDS dest = wave-uniform base + lane*16B
  __builtin_amdgcn_global_load_lds(
      (const __attribute__((address_space(1))) unsigned int*)g,
      (__attribute__((address_space(3))) unsigned int*)l, 16, 0, 0);
}

constexpr int Bn = 4, Tn = 2048, Cn = 2048, Hn = 16, Dh = 128;
constexpr int Kdim = Cn;
constexpr size_t SLOT = (size_t)Hn * Tn * Dh;  // 4,194,304 elems (8.39 MB bf16)
constexpr float kScale = 0.08838834764831845f * 1.4426950408889634f;  // 1/sqrt(Dh)*log2e

// ---------------- x fp32 -> bf16 (one pass; [8192][2048])
__global__ __launch_bounds__(256) void cvt_x(const float* __restrict__ in,
                                             bhalf* __restrict__ out) {
  const size_t i = ((size_t)blockIdx.x * 256 + threadIdx.x) * 8;
  const float4 a = *reinterpret_cast<const float4*>(in + i);
  const float4 b = *reinterpret_cast<const float4*>(in + i + 4);
  bhalf8 v;
  v[0] = (bhalf)a.x; v[1] = (bhalf)a.y; v[2] = (bhalf)a.z; v[3] = (bhalf)a.w;
  v[4] = (bhalf)b.x; v[5] = (bhalf)b.y; v[6] = (bhalf)b.z; v[7] = (bhalf)b.w;
  *reinterpret_cast<bhalf8*>(out + i) = v;
}

// ---------------- fp32 transpose+convert: out[c][r] = (bhalf)in[r*ldin + coff + c]
__global__ __launch_bounds__(256) void transpose_cvt(const float* __restrict__ in,
                                                     bhalf* __restrict__ out,
                                                     int ldin, int ldout, int coff) {
  __shared__ unsigned short tile[64][65];
  const int c0 = blockIdx.x * 64, r0 = blockIdx.y * 64;
  const int tx = threadIdx.x & 15, ty = threadIdx.x >> 4;
#pragma unroll
  for (int i = 0; i < 4; i++) {
    const int r = ty + i * 16;
    const float4 u = *reinterpret_cast<const float4*>(in + (size_t)(r0 + r) * ldin + coff + c0 + tx * 4);
    tile[r][tx * 4 + 0] = __builtin_bit_cast(unsigned short, (bhalf)u.x);
    tile[r][tx * 4 + 1] = __builtin_bit_cast(unsigned short, (bhalf)u.y);
    tile[r][tx * 4 + 2] = __builtin_bit_cast(unsigned short, (bhalf)u.z);
    tile[r][tx * 4 + 3] = __builtin_bit_cast(unsigned short, (bhalf)u.w);
  }
  __syncthreads();
#pragma unroll
  for (int i = 0; i < 4; i++) {
    const int c = ty + i * 16;
    ushort4 u;
    u.x = tile[tx * 4 + 0][c]; u.y = tile[tx * 4 + 1][c];
    u.z = tile[tx * 4 + 2][c]; u.w = tile[tx * 4 + 3][c];
    *reinterpret_cast<ushort4*>((unsigned short*)out + (size_t)(c0 + c) * ldout + r0 + tx * 4) = u;
  }
}

// ---------------- q,k GEMM, all-bf16: A = xb [8192][2048], Bt = W^T [4096][2048].
// 128x128x(BK=64), swizzled LDS, (256,4). q output pre-scaled by kScale so the
// flash softmax is exp2(s) with no per-element multiply.
__global__ __launch_bounds__(256, 4) void gemm_qk(const bhalf* __restrict__ A,
                                                  const bhalf* __restrict__ Bt,
                                                  const float* __restrict__ bias,
                                                  bhalf* __restrict__ oq,
                                                  bhalf* __restrict__ ok) {
  __shared__ __align__(16) bhalf sA[128 * 64];   // 16 KB, 16B chunk c at c^(row&7)
  __shared__ __align__(16) bhalf sB[128 * 64];   // 16 KB
  const int tid = threadIdx.x;
  const int lane = tid & 63, wv = tid >> 6;
  const int ln = lane & 15, quad = lane >> 4;
  const int wr = wv >> 1, wc = wv & 1;
  const int m0 = blockIdx.y * 128, n0 = blockIdx.x * 128;

  const floatx4 fzero = {0.f, 0.f, 0.f, 0.f};
  floatx4 acc[4][4];
#pragma unroll
  for (int i = 0; i < 4; i++)
#pragma unroll
    for (int j = 0; j < 4; j++) acc[i][j] = fzero;

  const int schunk = (lane & 7) ^ ((lane >> 3) & 7);
  const bhalf* aStage = A + (size_t)(m0 + wv * 32 + (lane >> 3)) * Kdim + schunk * 8;
  const bhalf* bStage = Bt + (size_t)(n0 + wv * 32 + (lane >> 3)) * Kdim + schunk * 8;
  bhalf* sAw = &sA[(wv * 32) * 64];
  bhalf* sBw = &sB[(wv * 32) * 64];

  for (int k0 = 0; k0 < Kdim; k0 += 64) {
#pragma unroll
    for (int j = 0; j < 4; j++) gload16(aStage + (size_t)j * 8 * Kdim + k0, sAw + j * 8 * 64);
#pragma unroll
    for (int j = 0; j < 4; j++) gload16(bStage + (size_t)j * 8 * Kdim + k0, sBw + j * 8 * 64);
    __syncthreads();
#pragma unroll
    for (int ks = 0; ks < 2; ks++) {
      bhalf8 af[4], bfr[4];
#pragma unroll
      for (int mi = 0; mi < 4; mi++)
        af[mi] = *reinterpret_cast<const bhalf8*>(
            &sA[(wr * 64 + mi * 16 + ln) * 64 + ((ks * 4 + quad) ^ (ln & 7)) * 8]);
#pragma unroll
      for (int ni = 0; ni < 4; ni++)
        bfr[ni] = *reinterpret_cast<const bhalf8*>(
            &sB[(wc * 64 + ni * 16 + ln) * 64 + ((ks * 4 + quad) ^ (ln & 7)) * 8]);
#pragma unroll
      for (int mi = 0; mi < 4; mi++)
#pragma unroll
        for (int ni = 0; ni < 4; ni++)
          acc[mi][ni] = MFMA16(af[mi], bfr[ni], acc[mi][ni]);
    }
    __syncthreads();
  }

  const int b = m0 >> 11, t0 = m0 & 2047;
  const int which = n0 >> 11;             // 0: q, 1: k
  const int h = (n0 & 2047) >> 7;
  bhalf* op = which == 0 ? oq : ok;
  const float scale = which == 0 ? kScale : 1.0f;  // fold softmax scale into q
  float bv[4];
#pragma unroll
  for (int ni = 0; ni < 4; ni++) bv[ni] = bias[n0 + wc * 64 + ni * 16 + ln];
  const size_t base = (size_t)b * (2 * SLOT) + ((size_t)h * Tn + t0) * Dh;
#pragma unroll
  for (int mi = 0; mi < 4; mi++)
#pragma unroll
    for (int ni = 0; ni < 4; ni++)
#pragma unroll
      for (int r = 0; r < 4; r++) {
        const int t = wr * 64 + mi * 16 + quad * 4 + r;  // C/D: row=quad*4+reg
        const int d = wc * 64 + ni * 16 + ln;            // C/D: col=lane&15
        op[base + (size_t)t * Dh + d] = (bhalf)((acc[mi][ni][r] + bv[ni]) * scale);
      }
}

// ---------------- v GEMM: A = x fp32 (staged fp32, cvt in frag load),
// Bt = W_v^T bf16 [2048][2048]. Swapped operands -> v^T [B,H,Dh,T] (+bias over d).
template <int MODE>
__global__ __launch_bounds__(256, 3) void gemm_xa(const float* __restrict__ A,
                                                  const bhalf* __restrict__ Bt,
                                                  const float* __restrict__ bias,
                                                  bhalf* __restrict__ oq,
                                                  bhalf* __restrict__ ok) {
  __shared__ __align__(16) float sA[128 * 64];   // 32 KB, 16B chunk c at c^(row&15)
  __shared__ __align__(16) bhalf sB[128 * 64];   // 16 KB, 16B chunk c at c^(row&7)
  const int tid = threadIdx.x;
  const int lane = tid & 63, wv = tid >> 6;
  const int ln = lane & 15, quad = lane >> 4;
  const int wr = wv >> 1, wc = wv & 1;  // 2x2 wave grid, 64x64 per wave
  const int m0 = blockIdx.y * 128, n0 = blockIdx.x * 128;

  const floatx4 fzero = {0.f, 0.f, 0.f, 0.f};
  floatx4 acc[4][4];
#pragma unroll
  for (int i = 0; i < 4; i++)
#pragma unroll
    for (int j = 0; j < 4; j++) acc[i][j] = fzero;

  const int schunkB = (lane & 7) ^ ((lane >> 3) & 7);
  const bhalf* bStage = Bt + (size_t)(n0 + wv * 32 + (lane >> 3)) * Kdim + schunkB * 8;
  bhalf* sBw = &sB[(wv * 32) * 64];
  const int rA = lane >> 4, cA = lane & 15;
  float* sAw = &sA[(wv * 32) * 64];

  for (int k0 = 0; k0 < Kdim; k0 += 64) {
#pragma unroll
    for (int j = 0; j < 8; j++) {
      const int rloc = j * 4 + rA;
      const int gc = cA ^ (rloc & 15);
      gload16(A + (size_t)(m0 + wv * 32 + rloc) * Kdim + k0 + gc * 4, sAw + (j * 4) * 64);
    }
#pragma unroll
    for (int j = 0; j < 4; j++) gload16(bStage + (size_t)j * 8 * Kdim + k0, sBw + j * 8 * 64);
    __syncthreads();
#pragma unroll
    for (int ks = 0; ks < 2; ks++) {
      bhalf8 af[4], bfr[4];
#pragma unroll
      for (int mi = 0; mi < 4; mi++) {
        const int row = wr * 64 + mi * 16 + ln;   // row&15 == ln
        const int c0c = ks * 8 + quad * 2;
        const float4 lo = *reinterpret_cast<const float4*>(&sA[row * 64 + ((c0c ^ ln) * 4)]);
        const float4 hi = *reinterpret_cast<const float4*>(&sA[row * 64 + (((c0c + 1) ^ ln) * 4)]);
        bhalf8 t;
        t[0] = (bhalf)lo.x; t[1] = (bhalf)lo.y; t[2] = (bhalf)lo.z; t[3] = (bhalf)lo.w;
        t[4] = (bhalf)hi.x; t[5] = (bhalf)hi.y; t[6] = (bhalf)hi.z; t[7] = (bhalf)hi.w;
        af[mi] = t;
      }
#pragma unroll
      for (int ni = 0; ni < 4; ni++)
        bfr[ni] = *reinterpret_cast<const bhalf8*>(
            &sB[(wc * 64 + ni * 16 + ln) * 64 + ((ks * 4 + quad) ^ (ln & 7)) * 8]);
#pragma unroll
      for (int i = 0; i < 4; i++)
#pragma unroll
        for (int j = 0; j < 4; j++) {
          if (MODE == 2)
            acc[i][j] = MFMA16(bfr[i], af[j], acc[i][j]);  // D^T: acc[ni][mi]
          else
            acc[i][j] = MFMA16(af[i], bfr[j], acc[i][j]);  // D:   acc[mi][ni]
        }
    }
    __syncthreads();
  }

  const int b = m0 >> 11, t0 = m0 & 2047;
  if (MODE == 0) {
    const int which = n0 >> 11;             // 0: q, 1: k
    const int h = (n0 & 2047) >> 7;
    bhalf* op = which == 0 ? oq : ok;
    float bv[4];
#pragma unroll
    for (int ni = 0; ni < 4; ni++) bv[ni] = bias[n0 + wc * 64 + ni * 16 + ln];
    const size_t base = (size_t)b * (2 * SLOT) + ((size_t)h * Tn + t0) * Dh;
#pragma unroll
    for (int mi = 0; mi < 4; mi++)
#pragma unroll
      for (int ni = 0; ni < 4; ni++)
#pragma unroll
        for (int r = 0; r < 4; r++) {
          const int t = wr * 64 + mi * 16 + quad * 4 + r;  // C/D: row=quad*4+reg
          const int d = wc * 64 + ni * 16 + ln;            // C/D: col=lane&15
          op[base + (size_t)t * Dh + d] = (bhalf)(acc[mi][ni][r] + bv[ni]);
        }
  } else {  // MODE 2: acc[ni][mi]; D^T row = d, col = t
    const int h = n0 >> 7;
    const size_t base = (size_t)(b * Hn + h) * Dh * Tn;
#pragma unroll
    for (int ni = 0; ni < 4; ni++)
#pragma unroll
      for (int mi = 0; mi < 4; mi++)
#pragma unroll
        for (int r = 0; r < 4; r++) {
          const int d = wc * 64 + ni * 16 + quad * 4 + r;
          const int t = t0 + wr * 64 + mi * 16 + ln;
          oq[base + (size_t)d * Tn + t] = (bhalf)(acc[ni][mi][r] + bias[n0 + d]);
        }
  }
}

// ---------------- proj GEMM: A = y bf16 [8192][2048], Bt = W_proj^T, out fp32 (+bias)
__global__ __launch_bounds__(256, 3) void gemm_proj(const bhalf* __restrict__ A,
                                                    const bhalf* __restrict__ Bt,
                                                    const float* __restrict__ bias,
                                                    float* __restrict__ of) {
  __shared__ __align__(16) bhalf sA[128 * 64];
  __shared__ __align__(16) bhalf sB[128 * 64];
  const int tid = threadIdx.x;
  const int lane = tid & 63, wv = tid >> 6;
  const int ln = lane & 15, quad = lane >> 4;
  const int wr = wv >> 1, wc = wv & 1;
  const int m0 = blockIdx.y * 128, n0 = blockIdx.x * 128;

  const floatx4 fzero = {0.f, 0.f, 0.f, 0.f};
  floatx4 acc[4][4];
#pragma unroll
  for (int i = 0; i < 4; i++)
#pragma unroll
    for (int j = 0; j < 4; j++) acc[i][j] = fzero;

  const int schunk = (lane & 7) ^ ((lane >> 3) & 7);
  const bhalf* aStage = A + (size_t)(m0 + wv * 32 + (lane >> 3)) * Kdim + schunk * 8;
  const bhalf* bStage = Bt + (size_t)(n0 + wv * 32 + (lane >> 3)) * Kdim + schunk * 8;
  bhalf* sAw = &sA[(wv * 32) * 64];
  bhalf* sBw = &sB[(wv * 32) * 64];

  for (int k0 = 0; k0 < Kdim; k0 += 64) {
#pragma unroll
    for (int j = 0; j < 4; j++) gload16(aStage + (size_t)j * 8 * Kdim + k0, sAw + j * 8 * 64);
#pragma unroll
    for (int j = 0; j < 4; j++) gload16(bStage + (size_t)j * 8 * Kdim + k0, sBw + j * 8 * 64);
    __syncthreads();
#pragma unroll
    for (int ks = 0; ks < 2; ks++) {
      bhalf8 af[4], bfr[4];
#pragma unroll
      for (int mi = 0; mi < 4; mi++)
        af[mi] = *reinterpret_cast<const bhalf8*>(
            &sA[(wr * 64 + mi * 16 + ln) * 64 + ((ks * 4 + quad) ^ (ln & 7)) * 8]);
#pragma unroll
      for (int ni = 0; ni < 4; ni++)
        bfr[ni] = *reinterpret_cast<const bhalf8*>(
            &sB[(wc * 64 + ni * 16 + ln) * 64 + ((ks * 4 + quad) ^ (ln & 7)) * 8]);
#pragma unroll
      for (int mi = 0; mi < 4; mi++)
#pragma unroll
        for (int ni = 0; ni < 4; ni++)
          acc[mi][ni] = MFMA16(af[mi], bfr[ni], acc[mi][ni]);
    }
    __syncthreads();
  }

  float bv[4];
#pragma unroll
  for (int ni = 0; ni < 4; ni++) bv[ni] = bias[n0 + wc * 64 + ni * 16 + ln];
#pragma unroll
  for (int mi = 0; mi < 4; mi++)
#pragma unroll
    for (int ni = 0; ni < 4; ni++)
#pragma unroll
      for (int r = 0; r < 4; r++) {
        const int row = m0 + wr * 64 + mi * 16 + quad * 4 + r;
        const int col = n0 + wc * 64 + ni * 16 + ln;
        of[(size_t)row * Cn + col] = acc[mi][ni][r] + bv[ni];
      }
}

// ---------------- flash attention v3c: QBLK=128 (32 q-rows/wave), KVBLK=64.
// One dispatch covers 2 batches (512 blocks, 1D). 48KB LDS, (256,2) no-spill.
// R13 chain fix: (1) rowsum kept as PER-LANE partials, butterfly deferred to
// epilogue (removes 32 shfl/iter + 4-deep serial chain); (2) q pre-scaled ->
// p = exp2(s) (no mul); (3) P-write moved BEFORE the V-wait barrier (sP is
// wave-private) so cvt+ds_write overlap the vmcnt(0) latency.
// Pipeline per 64-K-tile: [vmcnt(4)+bar] QK^T -> softmax(partial) -> P->sP ->
// [vmcnt(0)+bar] stageK(t+1) -> lgkm(0) -> PV -> [lgkm+bar] stageV(t+1).
__global__ __launch_bounds__(256, 2) void flash_attn2(const bhalf* __restrict__ qk,
                                                      const bhalf* __restrict__ vt,
                                                      bhalf* __restrict__ yb) {
  __shared__ __align__(16) bhalf sK[64 * 128];    // K tile [kpos][d], chunk^(row&15)
  __shared__ __align__(16) bhalf sVT[128 * 64];   // V^T tile [d][kpos], chunk^(row&7)
  __shared__ __align__(16) bhalf sP[128 * 64];    // P tile [qrow][kpos], chunk^(row&7)
  const int tid = threadIdx.x;
  const int lane = tid & 63, wv = tid >> 6;       // wave owns q-rows [wv*32, wv*32+32)
  const int ln = lane & 15, quad = lane >> 4;
  const int rl = lane >> 4, cl = lane & 15;       // K-staging row-in-group / chunk
  const int l = blockIdx.x;                        // 0..511 (2 batches)
  const int b = l >> 8;                            // 256 blocks per batch
  const int l5 = l & 255;
  const int h = ((l5 & 7) << 1) | ((l5 >> 3) & 1);
  const int t0q = (l5 >> 4) * 128;                 // 16 q-tiles of 128
  const bhalf* Qb  = qk + (size_t)b * 2 * SLOT;
  const bhalf* Kb  = Qb + SLOT;
  const bhalf* VTb = vt + (size_t)b * SLOT;
  bhalf* Ob        = yb + (size_t)b * SLOT;
  const size_t hb = (size_t)h * Tn * Dh;          // == h*Dh*Tn for vt

  bhalf8 qf[2][4];                                 // [mi][kd]: rows wv*32+mi*16+ln
#pragma unroll
  for (int mi = 0; mi < 2; mi++)
#pragma unroll
    for (int kd = 0; kd < 4; kd++)
      qf[mi][kd] = *reinterpret_cast<const bhalf8*>(
          Qb + hb + (size_t)(t0q + wv * 32 + mi * 16 + ln) * Dh + kd * 32 + quad * 8);

  const floatx4 fzero = {0.f, 0.f, 0.f, 0.f};
  floatx4 oAcc[2][8];
#pragma unroll
  for (int mi = 0; mi < 2; mi++)
#pragma unroll
    for (int di = 0; di < 8; di++) oAcc[mi][di] = fzero;
  float lrow[2][4] = {{0.f, 0.f, 0.f, 0.f}, {0.f, 0.f, 0.f, 0.f}};  // per-lane partial

  // 4 gload16 calls each (vmcnt counts: 4 per stage)
  auto stageK = [&](int t0k) {
#pragma unroll
    for (int j = 0; j < 4; j++) {
      const int rloc = wv * 16 + j * 4 + rl;      // 64 rows over 4 waves
      const int c = cl ^ (rloc & 15);
      gload16(Kb + hb + (size_t)(t0k + rloc) * Dh + c * 8, sK + (wv * 16 + j * 4) * 128);
    }
  };
  auto stageV = [&](int t0k) {
#pragma unroll
    for (int j = 0; j < 4; j++) {
      const int dloc = j * 32 + wv * 8 + (lane >> 3);  // 128 d-rows (64 B rows)
      const int c = (lane & 7) ^ (dloc & 7);
      gload16(VTb + hb + (size_t)dloc * Tn + t0k + c * 8, sVT + (j * 32 + wv * 8) * 64);
    }
  };

  // prologue: issue K(0) then V(0); clobber pins VMEM issue order (vmcnt counting)
  stageK(0);
  asm volatile("" ::: "memory");
  stageV(0);

  for (int t0k = 0; t0k < Tn; t0k += 64) {
    // K(t) ready: 4 newest outstanding are V(t) (iter 0 also drains older qf loads)
    asm volatile("s_waitcnt vmcnt(4)" ::: "memory");
    __builtin_amdgcn_s_barrier();
    asm volatile("" ::: "memory");

    // S = Q K^T (contract over d); each bfr feeds both mi
    floatx4 sAcc[2][4];
#pragma unroll
    for (int mi = 0; mi < 2; mi++)
#pragma unroll
      for (int ni = 0; ni < 4; ni++) sAcc[mi][ni] = fzero;
    __builtin_amdgcn_s_setprio(1);
#pragma unroll
    for (int kd = 0; kd < 4; kd++) {
#pragma unroll
      for (int ni = 0; ni < 4; ni++) {
        const bhalf8 bfr = *reinterpret_cast<const bhalf8*>(
            &sK[(ni * 16 + ln) * 128 + ((kd * 4 + quad) ^ ln) * 8]);
        sAcc[0][ni] = MFMA16(qf[0][kd], bfr, sAcc[0][ni]);
        sAcc[1][ni] = MFMA16(qf[1][kd], bfr, sAcc[1][ni]);
      }
    }
    __builtin_amdgcn_s_setprio(0);

    // softmax: p = exp2(s) (q pre-scaled); lrow keeps PER-LANE partials only
#pragma unroll
    for (int mi = 0; mi < 2; mi++)
#pragma unroll
      for (int r = 0; r < 4; r++) {
        float rs = 0.f;
#pragma unroll
        for (int ni = 0; ni < 4; ni++) {
          const float p = exp2f(sAcc[mi][ni][r]);
          sAcc[mi][ni][r] = p;
          rs += p;
        }
        lrow[mi][r] += rs;   // butterfly deferred to epilogue
      }

    // P (C/D layout) -> sP [qrow][kpos], chunk^(qrow&7). sP rows are WAVE-PRIVATE
    // (write rows wv*32+mi*16+quad*4+r; read rows wv*32+mi*16+ln) -> no barrier
    // needed; doing it HERE overlaps the V-load wait below.
#pragma unroll
    for (int mi = 0; mi < 2; mi++)
#pragma unroll
      for (int ni = 0; ni < 4; ni++)
#pragma unroll
        for (int r = 0; r < 4; r++) {
          const int qrow = wv * 32 + mi * 16 + quad * 4 + r;
          const int kcol = ni * 16 + ln;
          sP[qrow * 64 + (((kcol >> 3) ^ (qrow & 7)) * 8) + (kcol & 7)] =
              (bhalf)sAcc[mi][ni][r];
        }

    // V(t) ready; all waves past QK^T reads of sK -> safe to refill sK
    asm volatile("s_waitcnt vmcnt(0)" ::: "memory");
    __builtin_amdgcn_s_barrier();
    asm volatile("" ::: "memory");
    if (t0k + 64 < Tn) stageK(t0k + 64);   // overlaps PV

    asm volatile("s_waitcnt lgkmcnt(0)" ::: "memory");  // own P ds_writes landed

    // O += P V (contract over kpos); each bv feeds both mi
    __builtin_amdgcn_s_setprio(1);
#pragma unroll
    for (int kt = 0; kt < 2; kt++) {
      bhalf8 ap[2];
#pragma unroll
      for (int mi = 0; mi < 2; mi++)
        ap[mi] = *reinterpret_cast<const bhalf8*>(
            &sP[(wv * 32 + mi * 16 + ln) * 64 + ((kt * 4 + quad) ^ (ln & 7)) * 8]);
#pragma unroll
      for (int di = 0; di < 8; di++) {
        const bhalf8 bv = *reinterpret_cast<const bhalf8*>(
            &sVT[(di * 16 + ln) * 64 + ((kt * 4 + quad) ^ (ln & 7)) * 8]);
        oAcc[0][di] = MFMA16(ap[0], bv, oAcc[0][di]);
        oAcc[1][di] = MFMA16(ap[1], bv, oAcc[1][di]);
      }
    }
    __builtin_amdgcn_s_setprio(0);

    asm volatile("s_waitcnt lgkmcnt(0)" ::: "memory");
    __builtin_amdgcn_s_barrier();
    asm volatile("" ::: "memory");
    if (t0k + 64 < Tn) stageV(t0k + 64);   // overlaps next QK^T + softmax
  }

  // epilogue: finish the row-sum butterfly ONCE, then O / l -> y [T,C]
#pragma unroll
  for (int mi = 0; mi < 2; mi++)
#pragma unroll
    for (int r = 0; r < 4; r++) {
      float rs = lrow[mi][r];
      rs += __shfl_xor(rs, 1);
      rs += __shfl_xor(rs, 2);
      rs += __shfl_xor(rs, 4);
      rs += __shfl_xor(rs, 8);
      const float inv = 1.0f / rs;
      const int t = t0q + wv * 32 + mi * 16 + quad * 4 + r;
      const size_t rowb = (size_t)t * Cn + h * Dh;
#pragma unroll
      for (int di = 0; di < 8; di++)
        Ob[rowb + di * 16 + ln] = (bhalf)(oAcc[mi][di][r] * inv);
    }
}

extern "C" void kernel_launch(void* const* d_in, const int* in_sizes, int n_in,
                              void* d_out, int out_size, void* d_ws, size_t ws_size,
                              hipStream_t stream) {
  const float* x      = (const float*)d_in[0];
  const float* W_attn = (const float*)d_in[1];
  const float* b_attn = (const float*)d_in[2];
  const float* W_proj = (const float*)d_in[3];
  const float* b_proj = (const float*)d_in[4];
  float* out = (float*)d_out;
  bhalf* ws  = (bhalf*)d_ws;

  // slots (1 SLOT each):
  //   phase QKV: xb @ 0-3, wtQK @ 4-5 -> qk in d_out (xb dead after gemm_qk)
  //   phase V  : wtV @ 0, vt @ 2-5 (fp32-A gemm, reads x directly)
  //   phase FA : dispatch 0 = batches {0,1}: reads vt 2,3 writes y 0,1 (no overlap);
  //              dispatch 1 = batches {2,3}: reads vt 4,5 writes y 2,3 (overwrites
  //              vt 2,3 -- ordered after dispatch 0 by the stream boundary)
  //   phase PRJ: wtP @ 4, proj reads y@0-3 contiguous, writes d_out (qk dead)
  bhalf* xb   = ws;                 // [8192][2048] bf16
  bhalf* wtQK = ws + 4 * SLOT;      // [4096][2048]
  bhalf* wtV  = ws;                 // slot 0 (xb dead)
  bhalf* vt   = ws + 2 * SLOT;      // [B,H,Dh,T]
  bhalf* y    = ws;                 // y_b at slot b (contiguous [8192][2048])
  bhalf* wtP  = ws + 4 * SLOT;
  bhalf* qk   = (bhalf*)d_out;      // [q0,k0,q1,k1,...]; dead before proj

  // x -> bf16 once (removes fp32 staging from the big q,k GEMM)
  cvt_x<<<8192, 256, 0, stream>>>(x, xb);

  // q,k projection (one dispatch, N=4096), all-bf16 A; q pre-scaled by kScale
  transpose_cvt<<<dim3(64, 32), 256, 0, stream>>>(W_attn, wtQK, 3 * Cn, Kdim, 0);
  gemm_qk<<<dim3(32, 64), 256, 0, stream>>>(xb, wtQK, b_attn, qk, qk + SLOT);

  // v projection -> v^T (fp32-A path; xb slots 0-3 now dead, wtV reuses slot 0)
  transpose_cvt<<<dim3(32, 32), 256, 0, stream>>>(W_attn, wtV, 3 * Cn, Kdim, 2 * Cn);
  gemm_xa<2><<<dim3(16, 64), 256, 0, stream>>>(x, wtV, b_attn + 2 * Cn, vt, nullptr);

  // flash: 2 dispatches of 512 blocks (2 batches each) -- race-free slot reuse
  flash_attn2<<<512, 256, 0, stream>>>(qk, vt, y);
  flash_attn2<<<512, 256, 0, stream>>>(qk + 4 * SLOT, vt + 2 * SLOT, y + 2 * SLOT);

  // output projection (batched; overwrites q,k scratch in d_out)
  transpose_cvt<<<dim3(32, 32), 256, 0, stream>>>(W_proj, wtP, Kdim, Kdim, 0);
  gemm_proj<<<dim3(16, 64), 256, 0, stream>>>(y, wtP, b_proj, out);
}